// Round 7
// baseline (510.203 us; speedup 1.0000x reference)
//
#include <hip/hip_runtime.h>

// out[b,y,x] = sum_c sum_{p,q} feat1[b,c,y+p-2,x+q-2] * feat2[b,c,p,q]
// B=4096, C=512, H=W=4.
//
// R6 post-mortem: scratch persisted (500 MB = 16 calls x 64 B racc) with the
// runtime-index fixed -> the [&] LAMBDA was the remaining culprit: it takes
// racc's address (capture-by-ref), forcing it to scratch at each call.
// R4's hand-inlined identical compute was clean (VGPR 56, WRITE 258 KB).
// Fix: macro-expanded body — no capture, no address-taken accumulator.

__device__ __forceinline__ float4 shflx4(float4 v, int m) {
    float4 r;
    r.x = __shfl_xor(v.x, m, 64);
    r.y = __shfl_xor(v.y, m, 64);
    r.z = __shfl_xor(v.z, m, 64);
    r.w = __shfl_xor(v.w, m, 64);
    return r;
}

// racc[t][x] += sum_kk a[x+kk-2] * wrow(u^t)[kk]; all indices compile-time.
#define CORR_BODY(Av, Wv)                                                   \
    do {                                                                    \
        const float4 w1v = shflx4((Wv), 1);                                 \
        const float4 w2v = shflx4((Wv), 2);                                 \
        const float4 w3v = shflx4((Wv), 3);                                 \
        const float a0 = (Av).x, a1 = (Av).y, a2 = (Av).z, a3 = (Av).w;     \
        const float wr[4][4] = {                                            \
            {(Wv).x, (Wv).y, (Wv).z, (Wv).w},                               \
            {w1v.x, w1v.y, w1v.z, w1v.w},                                   \
            {w2v.x, w2v.y, w2v.z, w2v.w},                                   \
            {w3v.x, w3v.y, w3v.z, w3v.w}};                                  \
        _Pragma("unroll")                                                   \
        for (int t = 0; t < 4; ++t) {                                       \
            /* x=0: v = kk-2 valid for kk=2,3 -> a0,a1 */                   \
            racc[t][0] = fmaf(a0, wr[t][2], racc[t][0]);                    \
            racc[t][0] = fmaf(a1, wr[t][3], racc[t][0]);                    \
            /* x=1: kk=1,2,3 -> a0,a1,a2 */                                 \
            racc[t][1] = fmaf(a0, wr[t][1], racc[t][1]);                    \
            racc[t][1] = fmaf(a1, wr[t][2], racc[t][1]);                    \
            racc[t][1] = fmaf(a2, wr[t][3], racc[t][1]);                    \
            /* x=2: kk=0..3 -> a0..a3 */                                    \
            racc[t][2] = fmaf(a0, wr[t][0], racc[t][2]);                    \
            racc[t][2] = fmaf(a1, wr[t][1], racc[t][2]);                    \
            racc[t][2] = fmaf(a2, wr[t][2], racc[t][2]);                    \
            racc[t][2] = fmaf(a3, wr[t][3], racc[t][2]);                    \
            /* x=3: kk=0,1,2 -> a1,a2,a3 */                                 \
            racc[t][3] = fmaf(a1, wr[t][0], racc[t][3]);                    \
            racc[t][3] = fmaf(a2, wr[t][1], racc[t][3]);                    \
            racc[t][3] = fmaf(a3, wr[t][2], racc[t][3]);                    \
        }                                                                   \
    } while (0)

__global__ __launch_bounds__(256, 4) void corr_kernel(
        const float4* __restrict__ feat1,
        const float4* __restrict__ feat2,
        float* __restrict__ out) {
    const int tid  = threadIdx.x;
    const int lane = tid & 63;
    const int wv   = tid >> 6;                 // 0..3
    const int b    = blockIdx.x * 2 + (wv >> 1);
    const int half = wv & 1;                   // which half of the channels
    const int u    = lane & 3;                 // row (h) this lane owns

    // float4-unit base: lane i -> consecutive float4 (perfectly coalesced)
    const size_t kbase = (size_t)b * 2048 + (size_t)half * 1024 + lane;

    float racc[4][4];
    #pragma unroll
    for (int t = 0; t < 4; ++t)
        #pragma unroll
        for (int x = 0; x < 4; ++x) racc[t][x] = 0.f;

    float4 A0 = feat1[kbase];
    float4 W0 = feat2[kbase];
    float4 A1, W1;

    #pragma unroll
    for (int j = 0; j < 16; j += 2) {          // 16 chunks x 64 float4
        A1 = feat1[kbase + (size_t)(j + 1) * 64];
        W1 = feat2[kbase + (size_t)(j + 1) * 64];
        __builtin_amdgcn_sched_barrier(0);     // keep prefetch above compute
        CORR_BODY(A0, W0);
        if (j + 2 < 16) {
            A0 = feat1[kbase + (size_t)(j + 2) * 64];
            W0 = feat2[kbase + (size_t)(j + 2) * 64];
        }
        __builtin_amdgcn_sched_barrier(0);
        CORR_BODY(A1, W1);
    }

    // Per-lane remap: racc[t] = rowcorr(a_u, w_p) with p=u^t belongs to
    // out-row y = u-p+2. Enumerated per u (12 valid (u,p) pairs):
    //   y=2: t=0 all u.  y=1: u0,u2 <- t1; u1 <- t3.
    //   y=3: u1,u3 <- t1; u2 <- t3.  y=0: u0,u1 <- t2.
    float v16[16];
    #pragma unroll
    for (int x = 0; x < 4; ++x) {
        v16[2 * 4 + x] = racc[0][x];
        v16[1 * 4 + x] = (u == 0 || u == 2) ? racc[1][x]
                        : (u == 1 ? racc[3][x] : 0.f);
        v16[3 * 4 + x] = (u == 1 || u == 3) ? racc[1][x]
                        : (u == 2 ? racc[3][x] : 0.f);
        v16[0 * 4 + x] = (u < 2) ? racc[2][x] : 0.f;
    }

    // Value-splitting butterfly (verified R2/R4/R5/R6): after 4 steps lane l
    // holds component (l&15) summed over its 16-lane group; 2 xor steps
    // finish the wave.
    #pragma unroll
    for (int k = 0; k < 4; ++k) {
        const int m = 1 << k;
        const int pairs = 8 >> k;
        const bool sel = (lane >> k) & 1;
        float wtmp[8];
        #pragma unroll
        for (int p = 0; p < pairs; ++p) {
            float keep = sel ? v16[2 * p + 1] : v16[2 * p];
            float send = sel ? v16[2 * p]     : v16[2 * p + 1];
            float recv = __shfl_xor(send, m, 64);
            wtmp[p] = keep + recv;
        }
        #pragma unroll
        for (int p = 0; p < pairs; ++p) v16[p] = wtmp[p];
    }
    float r = v16[0];
    r += __shfl_xor(r, 16, 64);
    r += __shfl_xor(r, 32, 64);
    // lane l holds component (l&15) of this wave's half-channel partial sum

    __shared__ float red[4][16];
    if (lane < 16) red[wv][lane] = r;
    __syncthreads();
    if (tid < 32) {                            // combine halves, store 2 b's
        const int bs   = tid >> 4;
        const int comp = tid & 15;
        const float s = red[bs * 2 + 0][comp] + red[bs * 2 + 1][comp];
        out[(size_t)(blockIdx.x * 2 + bs) * 16 + comp] = s;
    }
}

extern "C" void kernel_launch(void* const* d_in, const int* in_sizes, int n_in,
                              void* d_out, int out_size, void* d_ws, size_t ws_size,
                              hipStream_t stream) {
    const float4* feat1 = (const float4*)d_in[0];
    const float4* feat2 = (const float4*)d_in[1];
    float* out = (float*)d_out;
    const int B = in_sizes[0] / (512 * 16);    // 4096
    corr_kernel<<<dim3(B / 2), dim3(256), 0, stream>>>(feat1, feat2, out);
}